// Round 23
// baseline (116.812 us; speedup 1.0000x reference)
//
#include <hip/hip_runtime.h>
#include <hip/hip_bf16.h>

// Problem dims (fixed by reference)
#define B_  2
#define LQ_ 1024
#define LK_ 10000
#define E_  256
#define H_  8
#define D_  32
#define NT_ ((LK_ + 63) / 64)  // 157
#define KVBLKS_ 625            // 20000 / 32
#define QBLKS_  64             // 2048 / 32

typedef __attribute__((ext_vector_type(8))) short bf16x8;
typedef __attribute__((ext_vector_type(4))) short bf16x4;
typedef __attribute__((ext_vector_type(4))) float f32x4;

#define LOG2E 1.4426950408889634f

// float -> bf16 via native cast (compiler pairs into v_cvt_pk_bf16_f32)
static __device__ __forceinline__ short bfc(float x) {
  __bf16 b = (__bf16)x;
  return __builtin_bit_cast(short, b);
}
static __device__ __forceinline__ float bf2f(short s) {
  return (float)__builtin_bit_cast(__bf16, s);
}

// fast exp2 (v_exp_f32). NOTE: __exp2f collides with a glibc identifier.
#if __has_builtin(__builtin_amdgcn_exp2f)
static __device__ __forceinline__ float ex2(float x) {
  return __builtin_amdgcn_exp2f(x);
}
#else
static __device__ __forceinline__ float ex2(float x) { return exp2f(x); }
#endif

#if __has_builtin(__builtin_amdgcn_mfma_f32_16x16x16bf16_1k)
static __device__ __forceinline__ f32x4 mfma_pv(bf16x4 a, bf16x4 b, f32x4 c) {
  return __builtin_amdgcn_mfma_f32_16x16x16bf16_1k(a, b, c, 0, 0, 0);
}
#else
static __device__ __forceinline__ f32x4 mfma_pv(bf16x4 a, bf16x4 b, f32x4 c) {
  asm volatile("s_nop 1\n\tv_mfma_f32_16x16x16_bf16 %0, %1, %2, %0"
               : "+v"(c) : "v"(a), "v"(b));
  return c;
}
#endif

// Tile barrier WITHOUT vmcnt drain [T4]: cross-wave hazard at the tile
// boundary is LDS-only. Global prefetch loads only feed registers, so they
// stay in flight across the barrier (R12: +21 us vs __syncthreads).
static __device__ __forceinline__ void tile_barrier() {
  __builtin_amdgcn_sched_barrier(0);
  asm volatile("s_waitcnt lgkmcnt(0)" ::: "memory");
  __builtin_amdgcn_s_barrier();
  __builtin_amdgcn_sched_barrier(0);
}

// m204 bijective XCD-chunked swizzle
static __device__ __forceinline__ int xcd_swizzle(int flat, int nwg) {
  const int xcd = flat & 7, rest = flat >> 3;
  const int q = nwg >> 3, r = nwg & 7;
  return (xcd < r ? xcd * (q + 1) : r * (q + 1) + (xcd - r) * q) + rest;
}

// split f32x8 (two float4) into hi/lo bf16x8 planes
static __device__ __forceinline__ void split8(const float4& a, const float4& b,
                                              bf16x8& hi, bf16x8& lo) {
  float v[8] = {a.x, a.y, a.z, a.w, b.x, b.y, b.z, b.w};
#pragma unroll
  for (int i = 0; i < 8; ++i) {
    const short h = bfc(v[i]);
    hi[i] = h;
    lo[i] = bfc(v[i] - bf2f(h));
  }
}

// ---------------------------------------------------------------------------
// wtrans4: Wt_bf16[n][k] = bf16(W[k][n]) for 4 weights in one launch.
// ---------------------------------------------------------------------------
__global__ __launch_bounds__(256) void wtrans4(
    const float* __restrict__ W0, const float* __restrict__ W1,
    const float* __restrict__ W2, const float* __restrict__ W3,
    unsigned short* __restrict__ T0, unsigned short* __restrict__ T1,
    unsigned short* __restrict__ T2, unsigned short* __restrict__ T3) {
  const float* W;
  unsigned short* T;
  switch (blockIdx.z) {
    case 0:  W = W0; T = T0; break;
    case 1:  W = W1; T = T1; break;
    case 2:  W = W2; T = T2; break;
    default: W = W3; T = T3; break;
  }
  __shared__ float ts[16][17];
  const int tx = threadIdx.x & 15;
  const int ty = threadIdx.x >> 4;
  const int k0 = blockIdx.x * 16;
  const int n0 = blockIdx.y * 16;
  ts[ty][tx] = W[(size_t)(k0 + ty) * 256 + n0 + tx];
  __syncthreads();
  T[(size_t)(n0 + ty) * 256 + k0 + tx] = (unsigned short)bfc(ts[tx][ty]);
}

// ---------------------------------------------------------------------------
// proj_all: fused KV + Q projections, barrier-free, LDS-free, 32 rows/wave.
// DEPTH-2 A prefetch (two register banks, kb fully unrolled).
// ---------------------------------------------------------------------------
__global__ __launch_bounds__(256) void proj_all(
    const float* __restrict__ bev, const float* __restrict__ queries,
    const unsigned short* __restrict__ Wtk, const unsigned short* __restrict__ Wtv,
    const unsigned short* __restrict__ Wtq,
    const float* __restrict__ bk, const float* __restrict__ bv,
    const float* __restrict__ bq,
    unsigned short* __restrict__ kout, unsigned short* __restrict__ vout,
    float* __restrict__ qout) {
  const int lane = threadIdx.x & 63;
  const int nt   = threadIdx.x >> 6;   // wave id = n-tile (0..3)
  const int lr   = lane & 15;
  const int oc   = lane >> 4;          // k-octet (0..3)
  const int n0   = nt * 64;

  const bool isQ = (blockIdx.x >= KVBLKS_);
  const int  m0  = (isQ ? (int)blockIdx.x - KVBLKS_ : (int)blockIdx.x) * 32;
  const float* A = isQ ? queries : bev;
  const unsigned short* W1 = isQ ? Wtq : Wtk;

  f32x4 ac1[2][4], ac2[2][4];
#pragma unroll
  for (int s = 0; s < 2; ++s)
#pragma unroll
    for (int q = 0; q < 4; ++q) {
      ac1[s][q] = (f32x4){0.f, 0.f, 0.f, 0.f};
      ac2[s][q] = (f32x4){0.f, 0.f, 0.f, 0.f};
    }

  const float* a0p = &A[(size_t)(m0 + lr) * 256 + oc * 8];
  const float* a1p = a0p + 16 * 256;

  float4 ab[2][4];
  ab[0][0] = *(const float4*)(a0p + 0);
  ab[0][1] = *(const float4*)(a0p + 4);
  ab[0][2] = *(const float4*)(a1p + 0);
  ab[0][3] = *(const float4*)(a1p + 4);
  ab[1][0] = *(const float4*)(a0p + 32);
  ab[1][1] = *(const float4*)(a0p + 36);
  ab[1][2] = *(const float4*)(a1p + 32);
  ab[1][3] = *(const float4*)(a1p + 36);

#pragma unroll
  for (int kb = 0; kb < 8; ++kb) {
    const int bk_ = kb & 1;

    const int wko = kb * 32 + oc * 8;
    bf16x8 w1[4], w2[4];
#pragma unroll
    for (int q = 0; q < 4; ++q) {
      w1[q] = *(const bf16x8*)&W1[(size_t)(n0 + q * 16 + lr) * 256 + wko];
      if (!isQ) w2[q] = *(const bf16x8*)&Wtv[(size_t)(n0 + q * 16 + lr) * 256 + wko];
    }

    bf16x8 ah0, al0, ah1, al1;
    split8(ab[bk_][0], ab[bk_][1], ah0, al0);
    split8(ab[bk_][2], ab[bk_][3], ah1, al1);

    if (kb < 6) {
      ab[bk_][0] = *(const float4*)(a0p + (kb + 2) * 32 + 0);
      ab[bk_][1] = *(const float4*)(a0p + (kb + 2) * 32 + 4);
      ab[bk_][2] = *(const float4*)(a1p + (kb + 2) * 32 + 0);
      ab[bk_][3] = *(const float4*)(a1p + (kb + 2) * 32 + 4);
    }

#pragma unroll
    for (int q = 0; q < 4; ++q) {
      ac1[0][q] = __builtin_amdgcn_mfma_f32_16x16x32_bf16(w1[q], ah0, ac1[0][q], 0, 0, 0);
      ac1[0][q] = __builtin_amdgcn_mfma_f32_16x16x32_bf16(w1[q], al0, ac1[0][q], 0, 0, 0);
      ac1[1][q] = __builtin_amdgcn_mfma_f32_16x16x32_bf16(w1[q], ah1, ac1[1][q], 0, 0, 0);
      ac1[1][q] = __builtin_amdgcn_mfma_f32_16x16x32_bf16(w1[q], al1, ac1[1][q], 0, 0, 0);
      if (!isQ) {
        ac2[0][q] = __builtin_amdgcn_mfma_f32_16x16x32_bf16(w2[q], ah0, ac2[0][q], 0, 0, 0);
        ac2[1][q] = __builtin_amdgcn_mfma_f32_16x16x32_bf16(w2[q], ah1, ac2[1][q], 0, 0, 0);
      }
    }
  }

#pragma unroll
  for (int s = 0; s < 2; ++s) {
#pragma unroll
    for (int q = 0; q < 4; ++q) {
      const int m = m0 + s * 16 + lr;
      const int n = n0 + q * 16 + oc * 4;
      if (isQ) {
        const float4 b4 = *(const float4*)&bq[n];
        float4 o;
        o.x = ac1[s][q][0] + b4.x; o.y = ac1[s][q][1] + b4.y;
        o.z = ac1[s][q][2] + b4.z; o.w = ac1[s][q][3] + b4.w;
        *(float4*)&qout[(size_t)m * 256 + n] = o;
      } else {
        const float4 bk4 = *(const float4*)&bk[n];
        const float4 bv4 = *(const float4*)&bv[n];
        ushort4 ok, ov;
        ok.x = (unsigned short)bfc(ac1[s][q][0] + bk4.x);
        ok.y = (unsigned short)bfc(ac1[s][q][1] + bk4.y);
        ok.z = (unsigned short)bfc(ac1[s][q][2] + bk4.z);
        ok.w = (unsigned short)bfc(ac1[s][q][3] + bk4.w);
        ov.x = (unsigned short)bfc(ac2[s][q][0] + bv4.x);
        ov.y = (unsigned short)bfc(ac2[s][q][1] + bv4.y);
        ov.z = (unsigned short)bfc(ac2[s][q][2] + bv4.z);
        ov.w = (unsigned short)bfc(ac2[s][q][3] + bv4.w);
        *(ushort4*)&kout[(size_t)m * 256 + n] = ok;
        *(ushort4*)&vout[(size_t)m * 256 + n] = ov;
      }
    }
  }
}

// ---------------------------------------------------------------------------
// proj_o: O-projection (split-A, f32 out), 32 rows/wave, depth-2 A prefetch.
// ---------------------------------------------------------------------------
__global__ __launch_bounds__(256) void proj_o(const float* __restrict__ A,
                                              const unsigned short* __restrict__ Wt,
                                              const float* __restrict__ bias,
                                              float* __restrict__ C) {
  const int lane = threadIdx.x & 63;
  const int nt   = threadIdx.x >> 6;
  const int lr   = lane & 15;
  const int oc   = lane >> 4;
  const int n0   = nt * 64;
  const int m0   = blockIdx.x * 32;

  f32x4 acc[2][4];
#pragma unroll
  for (int s = 0; s < 2; ++s)
#pragma unroll
    for (int q = 0; q < 4; ++q) acc[s][q] = (f32x4){0.f, 0.f, 0.f, 0.f};

  const float* a0p = &A[(size_t)(m0 + lr) * 256 + oc * 8];
  const float* a1p = a0p + 16 * 256;

  float4 ab[2][4];
  ab[0][0] = *(const float4*)(a0p + 0);
  ab[0][1] = *(const float4*)(a0p + 4);
  ab[0][2] = *(const float4*)(a1p + 0);
  ab[0][3] = *(const float4*)(a1p + 4);
  ab[1][0] = *(const float4*)(a0p + 32);
  ab[1][1] = *(const float4*)(a0p + 36);
  ab[1][2] = *(const float4*)(a1p + 32);
  ab[1][3] = *(const float4*)(a1p + 36);

#pragma unroll
  for (int kb = 0; kb < 8; ++kb) {
    const int bk_ = kb & 1;
    const int wko = kb * 32 + oc * 8;
    bf16x8 w[4];
#pragma unroll
    for (int q = 0; q < 4; ++q)
      w[q] = *(const bf16x8*)&Wt[(size_t)(n0 + q * 16 + lr) * 256 + wko];

    bf16x8 ah0, al0, ah1, al1;
    split8(ab[bk_][0], ab[bk_][1], ah0, al0);
    split8(ab[bk_][2], ab[bk_][3], ah1, al1);

    if (kb < 6) {
      ab[bk_][0] = *(const float4*)(a0p + (kb + 2) * 32 + 0);
      ab[bk_][1] = *(const float4*)(a0p + (kb + 2) * 32 + 4);
      ab[bk_][2] = *(const float4*)(a1p + (kb + 2) * 32 + 0);
      ab[bk_][3] = *(const float4*)(a1p + (kb + 2) * 32 + 4);
    }

#pragma unroll
    for (int q = 0; q < 4; ++q) {
      acc[0][q] = __builtin_amdgcn_mfma_f32_16x16x32_bf16(w[q], ah0, acc[0][q], 0, 0, 0);
      acc[0][q] = __builtin_amdgcn_mfma_f32_16x16x32_bf16(w[q], al0, acc[0][q], 0, 0, 0);
      acc[1][q] = __builtin_amdgcn_mfma_f32_16x16x32_bf16(w[q], ah1, acc[1][q], 0, 0, 0);
      acc[1][q] = __builtin_amdgcn_mfma_f32_16x16x32_bf16(w[q], al1, acc[1][q], 0, 0, 0);
    }
  }

#pragma unroll
  for (int s = 0; s < 2; ++s) {
#pragma unroll
    for (int q = 0; q < 4; ++q) {
      const int m = m0 + s * 16 + lr;
      const int n = n0 + q * 16 + oc * 4;
      const float4 b4 = *(const float4*)&bias[n];
      float4 o;
      o.x = acc[s][q][0] + b4.x; o.y = acc[s][q][1] + b4.y;
      o.z = acc[s][q][2] + b4.z; o.w = acc[s][q][3] + b4.w;
      *(float4*)&C[(size_t)m * 256 + n] = o;
    }
  }
}

// ---------------------------------------------------------------------------
// attn_mfma: K-SPLIT wave decomposition. Block = 128 q-rows, 4 waves
// w=(qh,kh): wave owns 64 q-rows (4 fragments) x 32 k-rows (2 subtiles).
// Each wave reads only HALF of the K and V LDS tiles per tile-step ->
// block LDS reads 32KB -> 16KB (total 44 -> 28 KB/tile, the binding pipe).
// Legal because fixed-base softmax makes l and O pure sums over k: the two
// k-halves combine with ONE cross-wave LDS reduction at the end (aliased
// onto the staging buffer, stride-9 floats = bank-conflict-free).
// MFMA/exp2 counts per block unchanged; occupancy unchanged (24KB, 4/CU).
// ---------------------------------------------------------------------------
__global__ __launch_bounds__(256, 4) void attn_mfma(const float* __restrict__ q,
                                                    const unsigned short* __restrict__ kbf,
                                                    const unsigned short* __restrict__ vbf,
                                                    float* __restrict__ Opart,
                                                    float* __restrict__ lpart,
                                                    float* __restrict__ o_direct,
                                                    int tiles_per_split, int nsplit) {
  const int nwg = 64 * gridDim.z;
  const int l   = xcd_swizzle(blockIdx.x + 8 * (blockIdx.y + 8 * blockIdx.z), nwg);
  const int qb   = l & 7;
  const int h    = (l >> 3) & 7;
  const int z    = l >> 6;
  const int s_id = z / B_;
  const int b    = z % B_;
  const int t    = threadIdx.x;
  const int lane = t & 63;
  const int w    = t >> 6;
  const int qh   = w >> 1;   // q-half: rows qb*128 + qh*64 ..
  const int kh   = w & 1;    // k-half: subtiles kh*2, kh*2+1
  const int lq   = lane & 15;
  const int grp  = lane >> 4;

  // staging buffer (24KB), aliased as f32 reduction scratch in the epilogue
  __shared__ __align__(16) char shraw[24576];
  typedef ushort KT[64][64];
  typedef ushort VT[32][64];
  KT* Klds = (KT*)shraw;               // [2][64][64] = 16KB
  VT* Vtld = (VT*)(shraw + 16384);     // [2][32][64] = 8KB

  const int t0 = s_id * tiles_per_split;
  const int t1 = min(NT_, t0 + tiles_per_split);

  // 4 q-fragments per wave: rows qbase + f*16
  const int qbase = qb * 128 + qh * 64 + lq;
  bf16x8 qf[4];
#pragma unroll
  for (int f = 0; f < 4; ++f) {
    const float* qp = &q[((size_t)(b * LQ_ + qbase + f * 16)) * E_ + h * D_ + grp * 8];
    const float4 x0 = *(const float4*)qp;
    const float4 x1 = *(const float4*)(qp + 4);
    qf[f][0] = bfc(x0.x * LOG2E); qf[f][1] = bfc(x0.y * LOG2E);
    qf[f][2] = bfc(x0.z * LOG2E); qf[f][3] = bfc(x0.w * LOG2E);
    qf[f][4] = bfc(x1.x * LOG2E); qf[f][5] = bfc(x1.y * LOG2E);
    qf[f][6] = bfc(x1.z * LOG2E); qf[f][7] = bfc(x1.w * LOG2E);
  }

  const int krow_l = t >> 2;
  const int kchunk = t & 3;
  const int vkp    = t >> 3;
  const int vd     = (t & 7) * 4;

  f32x4 lv[4];
  f32x4 accL[4], accH[4];   // d 0..15 / d 16..31 per fragment
#pragma unroll
  for (int f = 0; f < 4; ++f) {
    lv[f]   = (f32x4){0.f, 0.f, 0.f, 0.f};
    accL[f] = (f32x4){0.f, 0.f, 0.f, 0.f};
    accH[f] = (f32x4){0.f, 0.f, 0.f, 0.f};
  }

  const size_t kvrow0 = (size_t)b * LK_;

  uint4 kval; ushort4 v0, v1;
  auto load_tile = [&](int kn) {
    if (kn == NT_ - 1) {
      const int krow  = min(kn * 64 + krow_l, LK_ - 1);
      const int vrow0 = min(kn * 64 + 2 * vkp, LK_ - 1);
      const int vrow1 = min(kn * 64 + 2 * vkp + 1, LK_ - 1);
      kval = *(const uint4*)&kbf[(kvrow0 + krow) * E_ + h * D_ + kchunk * 8];
      v0 = *(const ushort4*)&vbf[(kvrow0 + vrow0) * E_ + h * D_ + vd];
      v1 = *(const ushort4*)&vbf[(kvrow0 + vrow1) * E_ + h * D_ + vd];
    } else {
      kval = *(const uint4*)&kbf[(kvrow0 + kn * 64 + krow_l) * E_ + h * D_ + kchunk * 8];
      v0 = *(const ushort4*)&vbf[(kvrow0 + kn * 64 + 2 * vkp) * E_ + h * D_ + vd];
      v1 = *(const ushort4*)&vbf[(kvrow0 + kn * 64 + 2 * vkp + 1) * E_ + h * D_ + vd];
    }
  };
  auto store_tile = [&](int buf) {
    *(uint4*)((char*)&Klds[buf][krow_l][0] + ((kchunk * 16) ^ ((krow_l & 7) << 4))) = kval;
#pragma unroll
    for (int i = 0; i < 4; ++i) {
      const int d = vd + i;
      *(ushort2*)((char*)&Vtld[buf][d][0] + ((vkp * 4) ^ ((d & 7) << 4))) =
          make_ushort2(((const unsigned short*)&v0)[i], ((const unsigned short*)&v1)[i]);
    }
  };

  load_tile(t0);
  store_tile(0);
  if (t0 + 1 < t1) load_tile(t0 + 1);
  tile_barrier();

  int cur = 0;
  for (int kt = t0; kt < t1; ++kt) {
    const int rem = LK_ - kt * 64;

    if (kt + 1 < t1) store_tile(cur ^ 1);
    if (kt + 2 < t1) load_tile(kt + 2);

    // this wave's 2 k-subtiles (ss = kh*2 + s); each feeds 4 q-fragments
#pragma unroll
    for (int s = 0; s < 2; ++s) {
      const int ss  = kh * 2 + s;
      const int row = ss * 16 + lq;
      const bf16x8 kf = *(const bf16x8*)((const char*)&Klds[cur][row][0] +
                                         ((grp * 16) ^ ((row & 7) << 4)));
      f32x4 p[4];
      __builtin_amdgcn_s_setprio(1);
#pragma unroll
      for (int f = 0; f < 4; ++f) {
        const f32x4 zero = {0.f, 0.f, 0.f, 0.f};
        p[f] = __builtin_amdgcn_mfma_f32_16x16x32_bf16(kf, qf[f], zero, 0, 0, 0);
      }
      __builtin_amdgcn_s_setprio(0);

      const bool vs = (rem >= 64) || (ss * 16 + grp * 4 < rem);
      bf16x4 pb[4];
#pragma unroll
      for (int f = 0; f < 4; ++f) {
#pragma unroll
        for (int r = 0; r < 4; ++r) {
          const float e = vs ? ex2(p[f][r]) : 0.f;
          lv[f][r] += e;
          pb[f][r] = bfc(e);
        }
      }

      const bf16x4 vfa = *(const bf16x4*)((const char*)&Vtld[cur][lq][0] +
                                          ((ss * 32 + grp * 8) ^ ((lq & 7) << 4)));
      const bf16x4 vfb = *(const bf16x4*)((const char*)&Vtld[cur][16 + lq][0] +
                                          ((ss * 32 + grp * 8) ^ (((16 + lq) & 7) << 4)));
      __builtin_amdgcn_s_setprio(1);
#pragma unroll
      for (int f = 0; f < 4; ++f) {
        accL[f] = mfma_pv(vfa, pb[f], accL[f]);
        accH[f] = mfma_pv(vfb, pb[f], accH[f]);
      }
      __builtin_amdgcn_s_setprio(0);
    }

    tile_barrier();
    cur ^= 1;
  }

  // lane-reduce l per fragment (sum over grp groups)
  float lf[4];
#pragma unroll
  for (int f = 0; f < 4; ++f) {
    float x = (lv[f][0] + lv[f][1]) + (lv[f][2] + lv[f][3]);
    x += __shfl_xor(x, 16);
    x += __shfl_xor(x, 32);
    lf[f] = x;
  }

  // cross-wave k-half reduction (LDS aliased onto the staging buffer).
  // layout: red[((qh*4+f)*64 + lane)*9 + j], j=0..7 acc, j=8 l. stride 9
  // floats per lane -> 9 coprime with 32 banks -> conflict-free.
  __syncthreads();
  float* red = (float*)shraw;  // 2*4*64*9*4B = 18KB <= 24KB
  if (kh == 1) {
#pragma unroll
    for (int f = 0; f < 4; ++f) {
      float* rp = &red[(size_t)(((qh * 4 + f) * 64 + lane) * 9)];
      rp[0] = accL[f][0]; rp[1] = accL[f][1]; rp[2] = accL[f][2]; rp[3] = accL[f][3];
      rp[4] = accH[f][0]; rp[5] = accH[f][1]; rp[6] = accH[f][2]; rp[7] = accH[f][3];
      rp[8] = lf[f];
    }
  }
  __syncthreads();
  if (kh == 0) {
#pragma unroll
    for (int f = 0; f < 4; ++f) {
      const float* rp = &red[(size_t)(((qh * 4 + f) * 64 + lane) * 9)];
      accL[f][0] += rp[0]; accL[f][1] += rp[1]; accL[f][2] += rp[2]; accL[f][3] += rp[3];
      accH[f][0] += rp[4]; accH[f][1] += rp[5]; accH[f][2] += rp[6]; accH[f][3] += rp[7];
      lf[f] += rp[8];
    }
    if (nsplit == 1) {
#pragma unroll
      for (int f = 0; f < 4; ++f) {
        const float inv = 1.f / lf[f];
        float* op = &o_direct[((size_t)(b * LQ_ + qbase + f * 16)) * E_ + h * D_];
#pragma unroll
        for (int r = 0; r < 4; ++r) {
          op[grp * 4 + r]      = accL[f][r] * inv;
          op[16 + grp * 4 + r] = accH[f][r] * inv;
        }
      }
    } else {
#pragma unroll
      for (int f = 0; f < 4; ++f) {
        const size_t pb_ = (size_t)s_id * (B_ * H_ * LQ_) +
                           ((size_t)b * H_ + h) * LQ_ + qbase + f * 16;
#pragma unroll
        for (int r = 0; r < 4; ++r) {
          Opart[pb_ * D_ + grp * 4 + r]      = accL[f][r];
          Opart[pb_ * D_ + 16 + grp * 4 + r] = accH[f][r];
        }
        if (grp == 0) lpart[pb_] = lf[f];
      }
    }
  }
}

// ---------------------------------------------------------------------------
// attn_merge: absolute-scale partials combine by plain sum.
// ---------------------------------------------------------------------------
__global__ __launch_bounds__(256) void attn_merge(const float* __restrict__ Opart,
                                                  const float* __restrict__ lpart,
                                                  float* __restrict__ o, int S) {
  const int idx = blockIdx.x * 256 + threadIdx.x;
  if (idx >= B_ * LQ_ * E_) return;
  const int e   = idx & (E_ - 1);
  const int row = idx >> 8;
  const int b   = row >> 10;
  const int qq  = row & (LQ_ - 1);
  const int h   = e >> 5;
  const int d   = e & (D_ - 1);
  const size_t base   = ((size_t)b * H_ + h) * LQ_ + qq;
  const size_t stride = (size_t)B_ * H_ * LQ_;

  float lsum = 0.f, osum = 0.f;
  for (int s = 0; s < S; ++s) {
    lsum += lpart[s * stride + base];
    osum += Opart[(s * stride + base) * D_ + d];
  }
  o[idx] = osum / lsum;
}

// ---------------------------------------------------------------------------
extern "C" void kernel_launch(void* const* d_in, const int* in_sizes, int n_in,
                              void* d_out, int out_size, void* d_ws, size_t ws_size,
                              hipStream_t stream) {
  const float* bev     = (const float*)d_in[0];
  const float* queries = (const float*)d_in[1];
  const float* Wq      = (const float*)d_in[2];
  const float* bq      = (const float*)d_in[3];
  const float* Wk      = (const float*)d_in[4];
  const float* bk      = (const float*)d_in[5];
  const float* Wv      = (const float*)d_in[6];
  const float* bv      = (const float*)d_in[7];
  const float* Wo      = (const float*)d_in[8];
  const float* bo      = (const float*)d_in[9];
  float* out = (float*)d_out;

  // ws: q f32 | k bf16 | v bf16 | o f32 | Wtq|Wtk|Wtv|Wto bf16 | Opart | l
  const size_t nq = (size_t)B_ * LQ_ * E_;  // 524288
  const size_t nk = (size_t)B_ * LK_ * E_;  // 5120000
  const size_t nw = (size_t)E_ * E_;        // 65536
  float*          qws = (float*)d_ws;
  unsigned short* kbf = (unsigned short*)(qws + nq);
  unsigned short* vbf = kbf + nk;
  float*          ows = (float*)(vbf + nk);
  unsigned short* Wtq = (unsigned short*)(ows + nq);
  unsigned short* Wtk = Wtq + nw;
  unsigned short* Wtv = Wtk + nw;
  unsigned short* Wto = Wtv + nw;
  float*          opart = (float*)(Wto + nw);

  const size_t base_bytes = (nq * 2) * sizeof(float) +
                            (nk * 2 + nw * 4) * sizeof(unsigned short);
  const size_t per_split_bytes = (size_t)B_ * H_ * LQ_ * (D_ + 1) * sizeof(float);
  const int cands[4] = {8, 4, 2, 1};
  int S = 1;
  for (int ci = 0; ci < 4; ++ci) {
    if (base_bytes + (size_t)cands[ci] * per_split_bytes <= ws_size) {
      S = cands[ci];
      break;
    }
  }

  wtrans4<<<dim3(16, 16, 4), 256, 0, stream>>>(Wq, Wk, Wv, Wo, Wtq, Wtk, Wtv, Wto);

  // fused: KV (blocks 0..624) + Q (blocks 625..688)
  proj_all<<<dim3(KVBLKS_ + QBLKS_), 256, 0, stream>>>(
      bev, queries, Wtk, Wtv, Wtq, bk, bv, bq, kbf, vbf, qws);

  if (S <= 1) {
    attn_mfma<<<dim3(8, H_, B_), 256, 0, stream>>>(
        qws, kbf, vbf, nullptr, nullptr, ows, NT_, 1);
  } else {
    float* lpart = opart + (size_t)S * B_ * H_ * LQ_ * D_;
    const int tps = (NT_ + S - 1) / S;
    attn_mfma<<<dim3(8, H_, B_ * S), 256, 0, stream>>>(
        qws, kbf, vbf, opart, lpart, nullptr, tps, S);
    attn_merge<<<dim3((B_ * LQ_ * E_ + 255) / 256), 256, 0, stream>>>(
        opart, lpart, ows, S);
  }

  proj_o<<<dim3(QBLKS_), 256, 0, stream>>>(ows, Wto, bo, out);
}

// Round 24
// 109.131 us; speedup vs baseline: 1.0704x; 1.0704x over previous
//
#include <hip/hip_runtime.h>
#include <hip/hip_bf16.h>

// Problem dims (fixed by reference)
#define B_  2
#define LQ_ 1024
#define LK_ 10000
#define E_  256
#define H_  8
#define D_  32
#define NT_ ((LK_ + 63) / 64)  // 157
#define KVBLKS_ 625            // 20000 / 32
#define QBLKS_  64             // 2048 / 32

typedef __attribute__((ext_vector_type(8))) short bf16x8;
typedef __attribute__((ext_vector_type(4))) short bf16x4;
typedef __attribute__((ext_vector_type(4))) float f32x4;

#define LOG2E 1.4426950408889634f

// float -> bf16 via native cast (compiler pairs into v_cvt_pk_bf16_f32)
static __device__ __forceinline__ short bfc(float x) {
  __bf16 b = (__bf16)x;
  return __builtin_bit_cast(short, b);
}
static __device__ __forceinline__ float bf2f(short s) {
  return (float)__builtin_bit_cast(__bf16, s);
}

// fast exp2 (v_exp_f32). NOTE: __exp2f collides with a glibc identifier.
#if __has_builtin(__builtin_amdgcn_exp2f)
static __device__ __forceinline__ float ex2(float x) {
  return __builtin_amdgcn_exp2f(x);
}
#else
static __device__ __forceinline__ float ex2(float x) { return exp2f(x); }
#endif

#if __has_builtin(__builtin_amdgcn_mfma_f32_16x16x16bf16_1k)
static __device__ __forceinline__ f32x4 mfma_pv(bf16x4 a, bf16x4 b, f32x4 c) {
  return __builtin_amdgcn_mfma_f32_16x16x16bf16_1k(a, b, c, 0, 0, 0);
}
#else
static __device__ __forceinline__ f32x4 mfma_pv(bf16x4 a, bf16x4 b, f32x4 c) {
  asm volatile("s_nop 1\n\tv_mfma_f32_16x16x16_bf16 %0, %1, %2, %0"
               : "+v"(c) : "v"(a), "v"(b));
  return c;
}
#endif

// Tile barrier WITHOUT vmcnt drain [T4]: cross-wave hazard at the tile
// boundary is LDS-only. Global prefetch loads only feed registers, so they
// stay in flight across the barrier (R12: +21 us vs __syncthreads).
static __device__ __forceinline__ void tile_barrier() {
  __builtin_amdgcn_sched_barrier(0);
  asm volatile("s_waitcnt lgkmcnt(0)" ::: "memory");
  __builtin_amdgcn_s_barrier();
  __builtin_amdgcn_sched_barrier(0);
}

// m204 bijective XCD-chunked swizzle
static __device__ __forceinline__ int xcd_swizzle(int flat, int nwg) {
  const int xcd = flat & 7, rest = flat >> 3;
  const int q = nwg >> 3, r = nwg & 7;
  return (xcd < r ? xcd * (q + 1) : r * (q + 1) + (xcd - r) * q) + rest;
}

// split f32x8 (two float4) into hi/lo bf16x8 planes
static __device__ __forceinline__ void split8(const float4& a, const float4& b,
                                              bf16x8& hi, bf16x8& lo) {
  float v[8] = {a.x, a.y, a.z, a.w, b.x, b.y, b.z, b.w};
#pragma unroll
  for (int i = 0; i < 8; ++i) {
    const short h = bfc(v[i]);
    hi[i] = h;
    lo[i] = bfc(v[i] - bf2f(h));
  }
}

// ---------------------------------------------------------------------------
// wtrans4: Wt_bf16[n][k] = bf16(W[k][n]) for 4 weights in one launch.
// ---------------------------------------------------------------------------
__global__ __launch_bounds__(256) void wtrans4(
    const float* __restrict__ W0, const float* __restrict__ W1,
    const float* __restrict__ W2, const float* __restrict__ W3,
    unsigned short* __restrict__ T0, unsigned short* __restrict__ T1,
    unsigned short* __restrict__ T2, unsigned short* __restrict__ T3) {
  const float* W;
  unsigned short* T;
  switch (blockIdx.z) {
    case 0:  W = W0; T = T0; break;
    case 1:  W = W1; T = T1; break;
    case 2:  W = W2; T = T2; break;
    default: W = W3; T = T3; break;
  }
  __shared__ float ts[16][17];
  const int tx = threadIdx.x & 15;
  const int ty = threadIdx.x >> 4;
  const int k0 = blockIdx.x * 16;
  const int n0 = blockIdx.y * 16;
  ts[ty][tx] = W[(size_t)(k0 + ty) * 256 + n0 + tx];
  __syncthreads();
  T[(size_t)(n0 + ty) * 256 + k0 + tx] = (unsigned short)bfc(ts[tx][ty]);
}

// ---------------------------------------------------------------------------
// proj_all: fused KV + Q projections, barrier-free, LDS-free, 32 rows/wave.
// Blocks [0,625): KV (bev -> K split-A hi/lo + V hi-only, bf16 out).
// Blocks [625,689): Q (queries -> qws, split-A, f32 out).
// DEPTH-2 A prefetch (two register banks, kb fully unrolled).
// ---------------------------------------------------------------------------
__global__ __launch_bounds__(256) void proj_all(
    const float* __restrict__ bev, const float* __restrict__ queries,
    const unsigned short* __restrict__ Wtk, const unsigned short* __restrict__ Wtv,
    const unsigned short* __restrict__ Wtq,
    const float* __restrict__ bk, const float* __restrict__ bv,
    const float* __restrict__ bq,
    unsigned short* __restrict__ kout, unsigned short* __restrict__ vout,
    float* __restrict__ qout) {
  const int lane = threadIdx.x & 63;
  const int nt   = threadIdx.x >> 6;   // wave id = n-tile (0..3)
  const int lr   = lane & 15;
  const int oc   = lane >> 4;          // k-octet (0..3)
  const int n0   = nt * 64;

  const bool isQ = (blockIdx.x >= KVBLKS_);
  const int  m0  = (isQ ? (int)blockIdx.x - KVBLKS_ : (int)blockIdx.x) * 32;
  const float* A = isQ ? queries : bev;
  const unsigned short* W1 = isQ ? Wtq : Wtk;

  f32x4 ac1[2][4], ac2[2][4];
#pragma unroll
  for (int s = 0; s < 2; ++s)
#pragma unroll
    for (int q = 0; q < 4; ++q) {
      ac1[s][q] = (f32x4){0.f, 0.f, 0.f, 0.f};
      ac2[s][q] = (f32x4){0.f, 0.f, 0.f, 0.f};
    }

  const float* a0p = &A[(size_t)(m0 + lr) * 256 + oc * 8];
  const float* a1p = a0p + 16 * 256;

  // depth-2 A prefetch: bank[kb&1] holds A(kb); prologue fills A(0), A(1)
  float4 ab[2][4];
  ab[0][0] = *(const float4*)(a0p + 0);
  ab[0][1] = *(const float4*)(a0p + 4);
  ab[0][2] = *(const float4*)(a1p + 0);
  ab[0][3] = *(const float4*)(a1p + 4);
  ab[1][0] = *(const float4*)(a0p + 32);
  ab[1][1] = *(const float4*)(a0p + 36);
  ab[1][2] = *(const float4*)(a1p + 32);
  ab[1][3] = *(const float4*)(a1p + 36);

#pragma unroll
  for (int kb = 0; kb < 8; ++kb) {
    const int bk_ = kb & 1;

    // W(kb) fragments (L2-hot); issued before split8 so their latency
    // overlaps the cvt VALU work
    const int wko = kb * 32 + oc * 8;
    bf16x8 w1[4], w2[4];
#pragma unroll
    for (int q = 0; q < 4; ++q) {
      w1[q] = *(const bf16x8*)&W1[(size_t)(n0 + q * 16 + lr) * 256 + wko];
      if (!isQ) w2[q] = *(const bf16x8*)&Wtv[(size_t)(n0 + q * 16 + lr) * 256 + wko];
    }

    // convert A(kb) (waits only on loads issued 2 iterations ago)
    bf16x8 ah0, al0, ah1, al1;
    split8(ab[bk_][0], ab[bk_][1], ah0, al0);
    split8(ab[bk_][2], ab[bk_][3], ah1, al1);

    // refill freed bank with A(kb+2)
    if (kb < 6) {
      ab[bk_][0] = *(const float4*)(a0p + (kb + 2) * 32 + 0);
      ab[bk_][1] = *(const float4*)(a0p + (kb + 2) * 32 + 4);
      ab[bk_][2] = *(const float4*)(a1p + (kb + 2) * 32 + 0);
      ab[bk_][3] = *(const float4*)(a1p + (kb + 2) * 32 + 4);
    }

#pragma unroll
    for (int q = 0; q < 4; ++q) {
      ac1[0][q] = __builtin_amdgcn_mfma_f32_16x16x32_bf16(w1[q], ah0, ac1[0][q], 0, 0, 0);
      ac1[0][q] = __builtin_amdgcn_mfma_f32_16x16x32_bf16(w1[q], al0, ac1[0][q], 0, 0, 0);
      ac1[1][q] = __builtin_amdgcn_mfma_f32_16x16x32_bf16(w1[q], ah1, ac1[1][q], 0, 0, 0);
      ac1[1][q] = __builtin_amdgcn_mfma_f32_16x16x32_bf16(w1[q], al1, ac1[1][q], 0, 0, 0);
      if (!isQ) {
        ac2[0][q] = __builtin_amdgcn_mfma_f32_16x16x32_bf16(w2[q], ah0, ac2[0][q], 0, 0, 0);
        ac2[1][q] = __builtin_amdgcn_mfma_f32_16x16x32_bf16(w2[q], ah1, ac2[1][q], 0, 0, 0);
      }
    }
  }

  // epilogue: m = m0+s*16+lr, n = n0+q*16+oc*4+(0..3)
#pragma unroll
  for (int s = 0; s < 2; ++s) {
#pragma unroll
    for (int q = 0; q < 4; ++q) {
      const int m = m0 + s * 16 + lr;
      const int n = n0 + q * 16 + oc * 4;
      if (isQ) {
        const float4 b4 = *(const float4*)&bq[n];
        float4 o;
        o.x = ac1[s][q][0] + b4.x; o.y = ac1[s][q][1] + b4.y;
        o.z = ac1[s][q][2] + b4.z; o.w = ac1[s][q][3] + b4.w;
        *(float4*)&qout[(size_t)m * 256 + n] = o;
      } else {
        const float4 bk4 = *(const float4*)&bk[n];
        const float4 bv4 = *(const float4*)&bv[n];
        ushort4 ok, ov;
        ok.x = (unsigned short)bfc(ac1[s][q][0] + bk4.x);
        ok.y = (unsigned short)bfc(ac1[s][q][1] + bk4.y);
        ok.z = (unsigned short)bfc(ac1[s][q][2] + bk4.z);
        ok.w = (unsigned short)bfc(ac1[s][q][3] + bk4.w);
        ov.x = (unsigned short)bfc(ac2[s][q][0] + bv4.x);
        ov.y = (unsigned short)bfc(ac2[s][q][1] + bv4.y);
        ov.z = (unsigned short)bfc(ac2[s][q][2] + bv4.z);
        ov.w = (unsigned short)bfc(ac2[s][q][3] + bv4.w);
        *(ushort4*)&kout[(size_t)m * 256 + n] = ok;
        *(ushort4*)&vout[(size_t)m * 256 + n] = ov;
      }
    }
  }
}

// ---------------------------------------------------------------------------
// proj_o: O-projection (split-A, f32 out), 32 rows/wave, depth-2 A prefetch.
// ---------------------------------------------------------------------------
__global__ __launch_bounds__(256) void proj_o(const float* __restrict__ A,
                                              const unsigned short* __restrict__ Wt,
                                              const float* __restrict__ bias,
                                              float* __restrict__ C) {
  const int lane = threadIdx.x & 63;
  const int nt   = threadIdx.x >> 6;
  const int lr   = lane & 15;
  const int oc   = lane >> 4;
  const int n0   = nt * 64;
  const int m0   = blockIdx.x * 32;

  f32x4 acc[2][4];
#pragma unroll
  for (int s = 0; s < 2; ++s)
#pragma unroll
    for (int q = 0; q < 4; ++q) acc[s][q] = (f32x4){0.f, 0.f, 0.f, 0.f};

  const float* a0p = &A[(size_t)(m0 + lr) * 256 + oc * 8];
  const float* a1p = a0p + 16 * 256;

  float4 ab[2][4];
  ab[0][0] = *(const float4*)(a0p + 0);
  ab[0][1] = *(const float4*)(a0p + 4);
  ab[0][2] = *(const float4*)(a1p + 0);
  ab[0][3] = *(const float4*)(a1p + 4);
  ab[1][0] = *(const float4*)(a0p + 32);
  ab[1][1] = *(const float4*)(a0p + 36);
  ab[1][2] = *(const float4*)(a1p + 32);
  ab[1][3] = *(const float4*)(a1p + 36);

#pragma unroll
  for (int kb = 0; kb < 8; ++kb) {
    const int bk_ = kb & 1;
    const int wko = kb * 32 + oc * 8;
    bf16x8 w[4];
#pragma unroll
    for (int q = 0; q < 4; ++q)
      w[q] = *(const bf16x8*)&Wt[(size_t)(n0 + q * 16 + lr) * 256 + wko];

    bf16x8 ah0, al0, ah1, al1;
    split8(ab[bk_][0], ab[bk_][1], ah0, al0);
    split8(ab[bk_][2], ab[bk_][3], ah1, al1);

    if (kb < 6) {
      ab[bk_][0] = *(const float4*)(a0p + (kb + 2) * 32 + 0);
      ab[bk_][1] = *(const float4*)(a0p + (kb + 2) * 32 + 4);
      ab[bk_][2] = *(const float4*)(a1p + (kb + 2) * 32 + 0);
      ab[bk_][3] = *(const float4*)(a1p + (kb + 2) * 32 + 4);
    }

#pragma unroll
    for (int q = 0; q < 4; ++q) {
      acc[0][q] = __builtin_amdgcn_mfma_f32_16x16x32_bf16(w[q], ah0, acc[0][q], 0, 0, 0);
      acc[0][q] = __builtin_amdgcn_mfma_f32_16x16x32_bf16(w[q], al0, acc[0][q], 0, 0, 0);
      acc[1][q] = __builtin_amdgcn_mfma_f32_16x16x32_bf16(w[q], ah1, acc[1][q], 0, 0, 0);
      acc[1][q] = __builtin_amdgcn_mfma_f32_16x16x32_bf16(w[q], al1, acc[1][q], 0, 0, 0);
    }
  }

#pragma unroll
  for (int s = 0; s < 2; ++s) {
#pragma unroll
    for (int q = 0; q < 4; ++q) {
      const int m = m0 + s * 16 + lr;
      const int n = n0 + q * 16 + oc * 4;
      const float4 b4 = *(const float4*)&bias[n];
      float4 o;
      o.x = acc[s][q][0] + b4.x; o.y = acc[s][q][1] + b4.y;
      o.z = acc[s][q][2] + b4.z; o.w = acc[s][q][3] + b4.w;
      *(float4*)&C[(size_t)m * 256 + n] = o;
    }
  }
}

// ---------------------------------------------------------------------------
// attn_mfma: best-known config (R16) — 128 q/block, 32 q/wave (two 16-row
// fragments), fixed-base softmax, f32x4 l-accum, T4 lgkmcnt-only tile
// barrier, 2-phase LDS dbuf, S=8.
// ---------------------------------------------------------------------------
__global__ __launch_bounds__(256, 4) void attn_mfma(const float* __restrict__ q,
                                                    const unsigned short* __restrict__ kbf,
                                                    const unsigned short* __restrict__ vbf,
                                                    float* __restrict__ Opart,
                                                    float* __restrict__ lpart,
                                                    float* __restrict__ o_direct,
                                                    int tiles_per_split, int nsplit) {
  const int nwg = 64 * gridDim.z;
  const int l   = xcd_swizzle(blockIdx.x + 8 * (blockIdx.y + 8 * blockIdx.z), nwg);
  const int qb   = l & 7;
  const int h    = (l >> 3) & 7;
  const int z    = l >> 6;
  const int s_id = z / B_;
  const int b    = z % B_;
  const int t    = threadIdx.x;
  const int lane = t & 63;
  const int w    = t >> 6;
  const int lq   = lane & 15;
  const int grp  = lane >> 4;

  __shared__ ushort Klds[2][64][64];
  __shared__ ushort Vtld[2][32][64];

  const int t0 = s_id * tiles_per_split;
  const int t1 = min(NT_, t0 + tiles_per_split);

  const int qrowA = qb * 128 + w * 32 + lq;
  const int qrowB = qrowA + 16;
  bf16x8 qfA, qfB;
  {
    const float* qpA = &q[((size_t)(b * LQ_ + qrowA)) * E_ + h * D_ + grp * 8];
    const float* qpB = &q[((size_t)(b * LQ_ + qrowB)) * E_ + h * D_ + grp * 8];
    const float4 a0 = *(const float4*)qpA;
    const float4 a1 = *(const float4*)(qpA + 4);
    const float4 b0 = *(const float4*)qpB;
    const float4 b1 = *(const float4*)(qpB + 4);
    qfA[0] = bfc(a0.x * LOG2E); qfA[1] = bfc(a0.y * LOG2E);
    qfA[2] = bfc(a0.z * LOG2E); qfA[3] = bfc(a0.w * LOG2E);
    qfA[4] = bfc(a1.x * LOG2E); qfA[5] = bfc(a1.y * LOG2E);
    qfA[6] = bfc(a1.z * LOG2E); qfA[7] = bfc(a1.w * LOG2E);
    qfB[0] = bfc(b0.x * LOG2E); qfB[1] = bfc(b0.y * LOG2E);
    qfB[2] = bfc(b0.z * LOG2E); qfB[3] = bfc(b0.w * LOG2E);
    qfB[4] = bfc(b1.x * LOG2E); qfB[5] = bfc(b1.y * LOG2E);
    qfB[6] = bfc(b1.z * LOG2E); qfB[7] = bfc(b1.w * LOG2E);
  }

  const int krow_l = t >> 2;
  const int kchunk = t & 3;
  const int vkp    = t >> 3;
  const int vd     = (t & 7) * 4;

  f32x4 lAv = {0.f, 0.f, 0.f, 0.f}, lBv = {0.f, 0.f, 0.f, 0.f};
  f32x4 a0A = {0.f, 0.f, 0.f, 0.f}, a1A = {0.f, 0.f, 0.f, 0.f};
  f32x4 a0B = {0.f, 0.f, 0.f, 0.f}, a1B = {0.f, 0.f, 0.f, 0.f};

  const size_t kvrow0 = (size_t)b * LK_;

  uint4 kval; ushort4 v0, v1;
  auto load_tile = [&](int kn) {
    if (kn == NT_ - 1) {
      const int krow  = min(kn * 64 + krow_l, LK_ - 1);
      const int vrow0 = min(kn * 64 + 2 * vkp, LK_ - 1);
      const int vrow1 = min(kn * 64 + 2 * vkp + 1, LK_ - 1);
      kval = *(const uint4*)&kbf[(kvrow0 + krow) * E_ + h * D_ + kchunk * 8];
      v0 = *(const ushort4*)&vbf[(kvrow0 + vrow0) * E_ + h * D_ + vd];
      v1 = *(const ushort4*)&vbf[(kvrow0 + vrow1) * E_ + h * D_ + vd];
    } else {
      kval = *(const uint4*)&kbf[(kvrow0 + kn * 64 + krow_l) * E_ + h * D_ + kchunk * 8];
      v0 = *(const ushort4*)&vbf[(kvrow0 + kn * 64 + 2 * vkp) * E_ + h * D_ + vd];
      v1 = *(const ushort4*)&vbf[(kvrow0 + kn * 64 + 2 * vkp + 1) * E_ + h * D_ + vd];
    }
  };
  auto store_tile = [&](int buf) {
    *(uint4*)((char*)&Klds[buf][krow_l][0] + ((kchunk * 16) ^ ((krow_l & 7) << 4))) = kval;
#pragma unroll
    for (int i = 0; i < 4; ++i) {
      const int d = vd + i;
      *(ushort2*)((char*)&Vtld[buf][d][0] + ((vkp * 4) ^ ((d & 7) << 4))) =
          make_ushort2(((const unsigned short*)&v0)[i], ((const unsigned short*)&v1)[i]);
    }
  };

  load_tile(t0);
  store_tile(0);
  if (t0 + 1 < t1) load_tile(t0 + 1);
  tile_barrier();

  int cur = 0;
  for (int kt = t0; kt < t1; ++kt) {
    const int rem = LK_ - kt * 64;

    if (kt + 1 < t1) store_tile(cur ^ 1);
    if (kt + 2 < t1) load_tile(kt + 2);

    f32x4 pA[4], pB[4];
    __builtin_amdgcn_s_setprio(1);
#pragma unroll
    for (int s = 0; s < 4; ++s) {
      const int row = s * 16 + lq;
      const bf16x8 kf = *(const bf16x8*)((const char*)&Klds[cur][row][0] +
                                         ((grp * 16) ^ ((row & 7) << 4)));
      const f32x4 zero = {0.f, 0.f, 0.f, 0.f};
      pA[s] = __builtin_amdgcn_mfma_f32_16x16x32_bf16(kf, qfA, zero, 0, 0, 0);
      pB[s] = __builtin_amdgcn_mfma_f32_16x16x32_bf16(kf, qfB, zero, 0, 0, 0);
    }
    __builtin_amdgcn_s_setprio(0);

    bf16x4 pbA[4], pbB[4];
    if (rem >= 64) {
#pragma unroll
      for (int s = 0; s < 4; ++s)
#pragma unroll
        for (int r = 0; r < 4; ++r) {
          const float eA = ex2(pA[s][r]);
          const float eB = ex2(pB[s][r]);
          lAv[r] += eA; lBv[r] += eB;
          pbA[s][r] = bfc(eA); pbB[s][r] = bfc(eB);
        }
    } else {
#pragma unroll
      for (int s = 0; s < 4; ++s) {
        const bool vs = (s * 16 + grp * 4) < rem;
#pragma unroll
        for (int r = 0; r < 4; ++r) {
          const float eA = vs ? ex2(pA[s][r]) : 0.f;
          const float eB = vs ? ex2(pB[s][r]) : 0.f;
          lAv[r] += eA; lBv[r] += eB;
          pbA[s][r] = bfc(eA); pbB[s][r] = bfc(eB);
        }
      }
    }

    __builtin_amdgcn_s_setprio(1);
#pragma unroll
    for (int s = 0; s < 4; ++s) {
      {
        const int row = lq;
        const bf16x4 vf = *(const bf16x4*)((const char*)&Vtld[cur][row][0] +
                                           ((s * 32 + grp * 8) ^ ((row & 7) << 4)));
        a0A = mfma_pv(vf, pbA[s], a0A);
        a0B = mfma_pv(vf, pbB[s], a0B);
      }
      {
        const int row = 16 + lq;
        const bf16x4 vf = *(const bf16x4*)((const char*)&Vtld[cur][row][0] +
                                           ((s * 32 + grp * 8) ^ ((row & 7) << 4)));
        a1A = mfma_pv(vf, pbA[s], a1A);
        a1B = mfma_pv(vf, pbB[s], a1B);
      }
    }
    __builtin_amdgcn_s_setprio(0);

    tile_barrier();
    cur ^= 1;
  }

  float lA = (lAv[0] + lAv[1]) + (lAv[2] + lAv[3]);
  float lB = (lBv[0] + lBv[1]) + (lBv[2] + lBv[3]);
  lA += __shfl_xor(lA, 16);
  lA += __shfl_xor(lA, 32);
  lB += __shfl_xor(lB, 16);
  lB += __shfl_xor(lB, 32);

  if (nsplit == 1) {
    const float invA = 1.f / lA;
    const float invB = 1.f / lB;
    float* opA = &o_direct[((size_t)(b * LQ_ + qrowA)) * E_ + h * D_];
    float* opB = &o_direct[((size_t)(b * LQ_ + qrowB)) * E_ + h * D_];
#pragma unroll
    for (int r = 0; r < 4; ++r) {
      opA[grp * 4 + r]      = a0A[r] * invA;
      opA[16 + grp * 4 + r] = a1A[r] * invA;
      opB[grp * 4 + r]      = a0B[r] * invB;
      opB[16 + grp * 4 + r] = a1B[r] * invB;
    }
  } else {
    const size_t pbA =
        (size_t)s_id * (B_ * H_ * LQ_) + ((size_t)b * H_ + h) * LQ_ + qrowA;
    const size_t pbB = pbA + 16;
#pragma unroll
    for (int r = 0; r < 4; ++r) {
      Opart[pbA * D_ + grp * 4 + r]      = a0A[r];
      Opart[pbA * D_ + 16 + grp * 4 + r] = a1A[r];
      Opart[pbB * D_ + grp * 4 + r]      = a0B[r];
      Opart[pbB * D_ + 16 + grp * 4 + r] = a1B[r];
    }
    if (grp == 0) {
      lpart[pbA] = lA;
      lpart[pbB] = lB;
    }
  }
}

// ---------------------------------------------------------------------------
// attn_merge: absolute-scale partials combine by plain sum.
// ---------------------------------------------------------------------------
__global__ __launch_bounds__(256) void attn_merge(const float* __restrict__ Opart,
                                                  const float* __restrict__ lpart,
                                                  float* __restrict__ o, int S) {
  const int idx = blockIdx.x * 256 + threadIdx.x;
  if (idx >= B_ * LQ_ * E_) return;
  const int e   = idx & (E_ - 1);
  const int row = idx >> 8;
  const int b   = row >> 10;
  const int qq  = row & (LQ_ - 1);
  const int h   = e >> 5;
  const int d   = e & (D_ - 1);
  const size_t base   = ((size_t)b * H_ + h) * LQ_ + qq;
  const size_t stride = (size_t)B_ * H_ * LQ_;

  float lsum = 0.f, osum = 0.f;
  for (int s = 0; s < S; ++s) {
    lsum += lpart[s * stride + base];
    osum += Opart[(s * stride + base) * D_ + d];
  }
  o[idx] = osum / lsum;
}

// ---------------------------------------------------------------------------
extern "C" void kernel_launch(void* const* d_in, const int* in_sizes, int n_in,
                              void* d_out, int out_size, void* d_ws, size_t ws_size,
                              hipStream_t stream) {
  const float* bev     = (const float*)d_in[0];
  const float* queries = (const float*)d_in[1];
  const float* Wq      = (const float*)d_in[2];
  const float* bq      = (const float*)d_in[3];
  const float* Wk      = (const float*)d_in[4];
  const float* bk      = (const float*)d_in[5];
  const float* Wv      = (const float*)d_in[6];
  const float* bv      = (const float*)d_in[7];
  const float* Wo      = (const float*)d_in[8];
  const float* bo      = (const float*)d_in[9];
  float* out = (float*)d_out;

  // ws: q f32 | k bf16 | v bf16 | o f32 | Wtq|Wtk|Wtv|Wto bf16 | Opart | l
  const size_t nq = (size_t)B_ * LQ_ * E_;  // 524288
  const size_t nk = (size_t)B_ * LK_ * E_;  // 5120000
  const size_t nw = (size_t)E_ * E_;        // 65536
  float*          qws = (float*)d_ws;
  unsigned short* kbf = (unsigned short*)(qws + nq);
  unsigned short* vbf = kbf + nk;
  float*          ows = (float*)(vbf + nk);
  unsigned short* Wtq = (unsigned short*)(ows + nq);
  unsigned short* Wtk = Wtq + nw;
  unsigned short* Wtv = Wtk + nw;
  unsigned short* Wto = Wtv + nw;
  float*          opart = (float*)(Wto + nw);

  const size_t base_bytes = (nq * 2) * sizeof(float) +
                            (nk * 2 + nw * 4) * sizeof(unsigned short);
  const size_t per_split_bytes = (size_t)B_ * H_ * LQ_ * (D_ + 1) * sizeof(float);
  const int cands[4] = {8, 4, 2, 1};
  int S = 1;
  for (int ci = 0; ci < 4; ++ci) {
    if (base_bytes + (size_t)cands[ci] * per_split_bytes <= ws_size) {
      S = cands[ci];
      break;
    }
  }

  wtrans4<<<dim3(16, 16, 4), 256, 0, stream>>>(Wq, Wk, Wv, Wo, Wtq, Wtk, Wtv, Wto);

  // fused: KV (blocks 0..624) + Q (blocks 625..688)
  proj_all<<<dim3(KVBLKS_ + QBLKS_), 256, 0, stream>>>(
      bev, queries, Wtk, Wtv, Wtq, bk, bv, bq, kbf, vbf, qws);

  if (S <= 1) {
    attn_mfma<<<dim3(8, H_, B_), 256, 0, stream>>>(
        qws, kbf, vbf, nullptr, nullptr, ows, NT_, 1);
  } else {
    float* lpart = opart + (size_t)S * B_ * H_ * LQ_ * D_;
    const int tps = (NT_ + S - 1) / S;
    attn_mfma<<<dim3(8, H_, B_ * S), 256, 0, stream>>>(
        qws, kbf, vbf, opart, lpart, nullptr, tps, S);
    attn_merge<<<dim3((B_ * LQ_ * E_ + 255) / 256), 256, 0, stream>>>(
        opart, lpart, ows, S);
  }

  proj_o<<<dim3(QBLKS_), 256, 0, stream>>>(ows, Wto, bo, out);
}